// Round 8
// baseline (307.335 us; speedup 1.0000x reference)
//
#include <hip/hip_runtime.h>
#include <stdint.h>

#define NB 16
#define NS 4096
#define NH 16
#define NC 1024

// ---- workspace layout (float offsets) ----
#define OFF_QHP   0u          // 262144   qhp[cs16][b][d]
#define OFF_QK    262144u     // 262144   qk[b][h][c]
#define OFF_QB    524288u     // 256      qb[b][h]
#define OFF_FLAG  524544u     // 64       mask dtype flag
#define OFF_SP    524608u     // 32768    Sp[b][sb64][ph32]
#define OFF_S     557376u     // 512      S[p][b][h]
#define OFF_ATT   557888u     // 2097152  att[b][s][p*16+h] (unnormalized exp)
#define OFF_CTXP  2655040u    // 8388608  ctxp[ss16][p][b][h][c]
#define OFF_CTX   11043648u   // 524288   ctx[p][b][h][c] (normalized)
#define OFF_CON   11567936u   // 32768    concat[p][b][dm]

// Detect how the harness materialized the bool mask.
__global__ void k_maskprobe(const uint32_t* __restrict__ m, int* __restrict__ flag) {
    __shared__ int sf, sg;
    if (threadIdx.x == 0) { sf = 0; sg = 0; }
    __syncthreads();
    uint32_t x = m[threadIdx.x];
    if (x == 0x3F800000u) atomicOr(&sf, 1);
    else if (x > 1u) atomicOr(&sg, 1);
    __syncthreads();
    if (threadIdx.x == 0) *flag = sf ? 2 : (sg ? 1 : 0);
}

// qhp[cs][b][d] = sum_{c in cs-chunk} q[b][c] * Wq[c][d]
__global__ __launch_bounds__(128) void k_qh(
    const float* __restrict__ q, const float* __restrict__ Wq, float* __restrict__ qhp)
{
    __shared__ float qs[64*16];   // [c][b]
    int dz = blockIdx.x, cs = blockIdx.y;
    int tid = threadIdx.x;
    int d = dz*128 + tid;
#pragma unroll
    for (int j = 0; j < 2; ++j) {
        int idx = j*128 + tid;
        int b = idx >> 4, c4 = (idx & 15) << 2;
        float4 t = *(const float4*)(q + (size_t)b*NC + cs*64 + c4);
        qs[(c4+0)*16 + b] = t.x; qs[(c4+1)*16 + b] = t.y;
        qs[(c4+2)*16 + b] = t.z; qs[(c4+3)*16 + b] = t.w;
    }
    __syncthreads();
    float acc[16];
#pragma unroll
    for (int b = 0; b < 16; ++b) acc[b] = 0.f;
#pragma unroll 4
    for (int c = 0; c < 64; ++c) {
        float w = Wq[(size_t)(cs*64 + c)*NC + d];
        const float4* qr = (const float4*)(qs + c*16);
        float4 q0 = qr[0], q1 = qr[1], q2 = qr[2], q3 = qr[3];
        acc[0]  = fmaf(w, q0.x, acc[0]);  acc[1]  = fmaf(w, q0.y, acc[1]);
        acc[2]  = fmaf(w, q0.z, acc[2]);  acc[3]  = fmaf(w, q0.w, acc[3]);
        acc[4]  = fmaf(w, q1.x, acc[4]);  acc[5]  = fmaf(w, q1.y, acc[5]);
        acc[6]  = fmaf(w, q1.z, acc[6]);  acc[7]  = fmaf(w, q1.w, acc[7]);
        acc[8]  = fmaf(w, q2.x, acc[8]);  acc[9]  = fmaf(w, q2.y, acc[9]);
        acc[10] = fmaf(w, q2.z, acc[10]); acc[11] = fmaf(w, q2.w, acc[11]);
        acc[12] = fmaf(w, q3.x, acc[12]); acc[13] = fmaf(w, q3.y, acc[13]);
        acc[14] = fmaf(w, q3.z, acc[14]); acc[15] = fmaf(w, q3.w, acc[15]);
    }
#pragma unroll
    for (int b = 0; b < 16; ++b) qhp[((size_t)cs*16 + b)*NC + d] = acc[b];
}

// qk[b][h][c] = sum_d qh[b][h64+d]*Wk[c][h64+d];  qh = sum_cs qhp + bq. qb = qh_h . bk_h
__global__ __launch_bounds__(128) void k_qk(
    const float* __restrict__ qhp, const float* __restrict__ bq,
    const float* __restrict__ Wk, const float* __restrict__ bk,
    float* __restrict__ qko, float* __restrict__ qbv)
{
    int h = blockIdx.x;
    int c = blockIdx.y*128 + threadIdx.x;
    __shared__ float qs[16*64];   // [b][dd]
    for (int j = 0; j < 8; ++j) {
        int idx = j*128 + threadIdx.x;
        int b = idx >> 6, dd = idx & 63;
        float a = bq[h*64 + dd];
#pragma unroll
        for (int cs = 0; cs < 16; ++cs) a += qhp[((size_t)cs*16 + b)*NC + h*64 + dd];
        qs[idx] = a;
    }
    __syncthreads();
    const float* wr = Wk + (size_t)c*NC + h*64;
    float acc[16];
#pragma unroll
    for (int b = 0; b < 16; ++b) acc[b] = 0.f;
#pragma unroll 4
    for (int d = 0; d < 64; ++d) {
        float w = wr[d];
#pragma unroll
        for (int b = 0; b < 16; ++b) acc[b] = fmaf(qs[b*64 + d], w, acc[b]);
    }
#pragma unroll
    for (int b = 0; b < 16; ++b) qko[((size_t)b*NH + h)*NC + c] = acc[b];
    if (blockIdx.y == 0 && threadIdx.x < 16) {
        int b = threadIdx.x; float a = 0.f;
        for (int d = 0; d < 64; ++d) a = fmaf(qs[b*64 + d], bk[h*64 + d], a);
        qbv[b*NH + h] = a;
    }
}

// Fused scores+exp+mask+att+S: grid (sb=64, b=16) = 1024 blocks, 256 thr.
// Quad-of-4 lanes owns ONE k-row: lane ph reads bytes ph*16..+16 of the row's
// 64B window (full line consumption, zero overfetch). q staged in 4 chunks of
// 256c x 16h (20.5 KB LDS) -> 4 blocks/CU, 4 waves/SIMD.
#define QTS 20   // qt row stride (80B: 16B-aligned for b128 reads)
__global__ __launch_bounds__(256) void k_scoresG2(
    const float* __restrict__ kk, const float* __restrict__ qkm,
    const float* __restrict__ qbv, const void* __restrict__ mask,
    const int* __restrict__ flagp, float* __restrict__ att, float* __restrict__ Sp)
{
    __shared__ float qt[256*QTS];    // 20 KB [c_in_chunk][h]
    __shared__ float red[4][2][16];
    int sb = blockIdx.x, b = blockIdx.y;
    int tid = threadIdx.x;
    int g = tid >> 2, ph = tid & 3;
    int s = sb*64 + g;
    const float* kbase = kk + ((size_t)b*NS + s)*NC + ph*4;
    float acc[16];
#pragma unroll
    for (int h = 0; h < 16; ++h) acc[h] = 0.f;

    for (int cz = 0; cz < 4; ++cz) {
        __syncthreads();
#pragma unroll
        for (int j = 0; j < 16; ++j) {
            int idx = j*256 + tid;
            int h = idx >> 8, c = idx & 255;
            qt[c*QTS + h] = qkm[((size_t)b*NH + h)*NC + cz*256 + c];
        }
        __syncthreads();
#pragma unroll
        for (int w = 0; w < 16; ++w) {
            float4 kv = *(const float4*)(kbase + cz*256 + w*16);
#pragma unroll
            for (int j = 0; j < 4; ++j) {
                float kc = (j == 0) ? kv.x : (j == 1) ? kv.y : (j == 2) ? kv.z : kv.w;
                const float* qp = qt + (w*16 + ph*4 + j)*QTS;
                float4 q0 = *(const float4*)(qp + 0);
                float4 q1 = *(const float4*)(qp + 4);
                float4 q2 = *(const float4*)(qp + 8);
                float4 q3 = *(const float4*)(qp + 12);
                acc[0]  = fmaf(kc, q0.x, acc[0]);
                acc[1]  = fmaf(kc, q0.y, acc[1]);
                acc[2]  = fmaf(kc, q0.z, acc[2]);
                acc[3]  = fmaf(kc, q0.w, acc[3]);
                acc[4]  = fmaf(kc, q1.x, acc[4]);
                acc[5]  = fmaf(kc, q1.y, acc[5]);
                acc[6]  = fmaf(kc, q1.z, acc[6]);
                acc[7]  = fmaf(kc, q1.w, acc[7]);
                acc[8]  = fmaf(kc, q2.x, acc[8]);
                acc[9]  = fmaf(kc, q2.y, acc[9]);
                acc[10] = fmaf(kc, q2.z, acc[10]);
                acc[11] = fmaf(kc, q2.w, acc[11]);
                acc[12] = fmaf(kc, q3.x, acc[12]);
                acc[13] = fmaf(kc, q3.y, acc[13]);
                acc[14] = fmaf(kc, q3.z, acc[14]);
                acc[15] = fmaf(kc, q3.w, acc[15]);
            }
        }
    }
    // quad butterfly completes the c-dot; all 4 lanes hold all 16 totals
#pragma unroll
    for (int h = 0; h < 16; ++h) {
        acc[h] += __shfl_xor(acc[h], 1, 64);
        acc[h] += __shfl_xor(acc[h], 2, 64);
    }

    // epilogue: lane covers 4 heads h0..h0+3 of its row s
    int h0 = ph*4;
    int fl = *flagp;
    unsigned mbits = 0;
    if (fl == 1) {
        const uint8_t* mp = (const uint8_t*)mask + (size_t)(b*NH + h0)*NS + s;
#pragma unroll
        for (int j = 0; j < 4; ++j) if (mp[(size_t)j*NS]) mbits |= (1u << j);
    } else if (fl == 2) {
        const float* mp = (const float*)mask + (size_t)(b*NH + h0)*NS + s;
#pragma unroll
        for (int j = 0; j < 4; ++j) if (mp[(size_t)j*NS] != 0.f) mbits |= (1u << j);
    } else {
        const int* mp = (const int*)mask + (size_t)(b*NH + h0)*NS + s;
#pragma unroll
        for (int j = 0; j < 4; ++j) if (mp[(size_t)j*NS]) mbits |= (1u << j);
    }
    float p0[4], p1[4], r0[4], r1[4];
#pragma unroll
    for (int j = 0; j < 4; ++j) {
        float val = (acc[h0+j] + qbv[b*NH + h0 + j]) * 0.125f;
        p0[j] = __expf(val);
        p1[j] = (mbits >> j & 1u) ? 1.0f : p0[j];
        r0[j] = p0[j]; r1[j] = p1[j];
    }
    float* arow = att + ((size_t)b*NS + s)*32;
    *(float4*)(arow + h0)      = make_float4(p0[0], p0[1], p0[2], p0[3]);
    *(float4*)(arow + 16 + h0) = make_float4(p1[0], p1[1], p1[2], p1[3]);

    // S partials: reduce over rows (g bits) within wave, then block
#pragma unroll
    for (int off = 4; off < 64; off <<= 1)
#pragma unroll
        for (int j = 0; j < 4; ++j) {
            r0[j] += __shfl_xor(r0[j], off, 64);
            r1[j] += __shfl_xor(r1[j], off, 64);
        }
    int wv = tid >> 6;
    if ((tid & 63) < 4) {
#pragma unroll
        for (int j = 0; j < 4; ++j) {
            red[wv][0][(tid & 3)*4 + j] = r0[j];
            red[wv][1][(tid & 3)*4 + j] = r1[j];
        }
    }
    __syncthreads();
    if (tid < 32) {
        int pa = tid >> 4, h = tid & 15;
        Sp[((size_t)b*64 + sb)*32 + tid] =
            red[0][pa][h] + red[1][pa][h] + red[2][pa][h] + red[3][pa][h];
    }
}

// S[p][b][h] = sum_sb Sp[b][sb][p*16+h]
__global__ void k_sred(const float* __restrict__ Sp, float* __restrict__ S) {
    int t = blockIdx.x*256 + threadIdx.x;   // 512 total
    int p = t >> 8, b = (t >> 4) & 15, h = t & 15;
    float a = 0.f;
#pragma unroll
    for (int sb = 0; sb < 64; ++sb) a += Sp[((size_t)b*64 + sb)*32 + p*16 + h];
    S[t] = a;
}

// ctx partials: ctxp[ss][p][b][h][c] = sum_{s in 256-row chunk} att[b][s][p,h]*v[b][s][c]
// grid (16b x 16ss, 4cz) = 1024 blocks -> ~3 blocks/CU.
__global__ __launch_bounds__(256,2) void k_ctx(
    const float* __restrict__ v, const float* __restrict__ att, float* __restrict__ ctxp)
{
    __shared__ float al[64*32];
    __shared__ float buf[8192];
    int b = blockIdx.x & 15, ss = blockIdx.x >> 4;
    int cz = blockIdx.y;
    int tid = threadIdx.x, ct = tid & 63, rg = tid >> 6;
    int s1 = ss * 256;
    float acc[32][4];
#pragma unroll
    for (int i = 0; i < 32; ++i)
#pragma unroll
        for (int j = 0; j < 4; ++j) acc[i][j] = 0.f;

    for (int c0 = 0; c0 < 256; c0 += 64) {
        __syncthreads();
#pragma unroll
        for (int jj = 0; jj < 2; ++jj) {
            int idx = jj*256 + tid;
            ((float4*)al)[idx] = ((const float4*)(att + ((size_t)b*NS + s1 + c0)*32))[idx];
        }
        __syncthreads();
        for (int it = 0; it < 16; ++it) {
            int rl = c0 + it*4 + rg;
            float4 vv = *(const float4*)(v + ((size_t)b*NS + s1 + rl)*NC + cz*256 + ct*4);
            const float4* ar = (const float4*)(al + (it*4 + rg)*32);
#pragma unroll
            for (int u = 0; u < 8; ++u) {
                float4 aw = ar[u];
                acc[u*4+0][0] = fmaf(aw.x, vv.x, acc[u*4+0][0]);
                acc[u*4+0][1] = fmaf(aw.x, vv.y, acc[u*4+0][1]);
                acc[u*4+0][2] = fmaf(aw.x, vv.z, acc[u*4+0][2]);
                acc[u*4+0][3] = fmaf(aw.x, vv.w, acc[u*4+0][3]);
                acc[u*4+1][0] = fmaf(aw.y, vv.x, acc[u*4+1][0]);
                acc[u*4+1][1] = fmaf(aw.y, vv.y, acc[u*4+1][1]);
                acc[u*4+1][2] = fmaf(aw.y, vv.z, acc[u*4+1][2]);
                acc[u*4+1][3] = fmaf(aw.y, vv.w, acc[u*4+1][3]);
                acc[u*4+2][0] = fmaf(aw.z, vv.x, acc[u*4+2][0]);
                acc[u*4+2][1] = fmaf(aw.z, vv.y, acc[u*4+2][1]);
                acc[u*4+2][2] = fmaf(aw.z, vv.z, acc[u*4+2][2]);
                acc[u*4+2][3] = fmaf(aw.z, vv.w, acc[u*4+2][3]);
                acc[u*4+3][0] = fmaf(aw.w, vv.x, acc[u*4+3][0]);
                acc[u*4+3][1] = fmaf(aw.w, vv.y, acc[u*4+3][1]);
                acc[u*4+3][2] = fmaf(aw.w, vv.z, acc[u*4+3][2]);
                acc[u*4+3][3] = fmaf(aw.w, vv.w, acc[u*4+3][3]);
            }
        }
    }
    for (int pr = 0; pr < 4; ++pr) {
        __syncthreads();
#pragma unroll
        for (int u = 0; u < 8; ++u) {
            int ph = pr*8 + u;
            float4 t; t.x = acc[ph][0]; t.y = acc[ph][1]; t.z = acc[ph][2]; t.w = acc[ph][3];
            ((float4*)buf)[(rg*8 + u)*64 + ct] = t;
        }
        __syncthreads();
#pragma unroll
        for (int kx = 0; kx < 2; ++kx) {
            int i = kx*256 + tid;
            int u2 = i >> 6, c2 = i & 63;
            float4 s = ((float4*)buf)[(size_t)(0*8 + u2)*64 + c2];
#pragma unroll
            for (int r2 = 1; r2 < 4; ++r2) {
                float4 t = ((float4*)buf)[(size_t)(r2*8 + u2)*64 + c2];
                s.x += t.x; s.y += t.y; s.z += t.z; s.w += t.w;
            }
            int ph = pr*8 + u2, p = ph >> 4, h = ph & 15;
            *(float4*)(ctxp + ((((size_t)ss*2 + p)*NB + b)*NH + h)*NC + cz*256 + c2*4) = s;
        }
    }
}

// reduce ss partials + normalize by S
__global__ void k_ctxred(const float* __restrict__ ctxp, const float* __restrict__ S,
                         float* __restrict__ ctx) {
    size_t i = (size_t)blockIdx.x * 256 + threadIdx.x;
    float a = 0.f;
#pragma unroll
    for (int ss = 0; ss < 16; ++ss) a += ctxp[(size_t)ss*524288 + i];
    ctx[i] = a / S[i >> 10];
}

// concat[p][b][d] = ctx[p][b][h(d)][:] . Wv[:, d] + bv[d]
__global__ __launch_bounds__(256) void k_outh(
    const float* __restrict__ ctx, const float* __restrict__ Wv,
    const float* __restrict__ bv, float* __restrict__ con)
{
    int b = blockIdx.y, p = blockIdx.z;
    int d = blockIdx.x*256 + threadIdx.x;
    int h0 = blockIdx.x*4;
    __shared__ float cl[4*NC];
    for (int i = threadIdx.x; i < 4*NC; i += 256)
        cl[i] = ctx[(((size_t)p*NB + b)*NH + h0 + (i >> 10))*NC + (i & 1023)];
    __syncthreads();
    const float* c2 = cl + ((threadIdx.x >> 6) << 10);
    float a0=0.f,a1=0.f,a2=0.f,a3=0.f;
    for (int c = 0; c < NC; c += 4) {
        a0 = fmaf(c2[c+0], Wv[(size_t)(c+0)*NC + d], a0);
        a1 = fmaf(c2[c+1], Wv[(size_t)(c+1)*NC + d], a1);
        a2 = fmaf(c2[c+2], Wv[(size_t)(c+2)*NC + d], a2);
        a3 = fmaf(c2[c+3], Wv[(size_t)(c+3)*NC + d], a3);
    }
    con[((size_t)p*NB + b)*NC + d] = (a0+a1)+(a2+a3) + bv[d];
}

// out[p][b][o] = concat[p][b][:] . Wo[:, o] + bo[o]
__global__ __launch_bounds__(256) void k_out(
    const float* __restrict__ con, const float* __restrict__ Wo,
    const float* __restrict__ bo, float* __restrict__ out)
{
    int b = blockIdx.y, p = blockIdx.z;
    int o = blockIdx.x*256 + threadIdx.x;
    __shared__ float cl[NC];
    for (int i = threadIdx.x; i < NC; i += 256)
        cl[i] = con[((size_t)p*NB + b)*NC + i];
    __syncthreads();
    float a0=0.f,a1=0.f,a2=0.f,a3=0.f;
    for (int m = 0; m < NC; m += 4) {
        a0 = fmaf(cl[m+0], Wo[(size_t)(m+0)*NC + o], a0);
        a1 = fmaf(cl[m+1], Wo[(size_t)(m+1)*NC + o], a1);
        a2 = fmaf(cl[m+2], Wo[(size_t)(m+2)*NC + o], a2);
        a3 = fmaf(cl[m+3], Wo[(size_t)(m+3)*NC + o], a3);
    }
    out[(size_t)p*NB*NC + (size_t)b*NC + o] = (a0+a1)+(a2+a3) + bo[o];
}

extern "C" void kernel_launch(void* const* d_in, const int* in_sizes, int n_in,
                              void* d_out, int out_size, void* d_ws, size_t ws_size,
                              hipStream_t stream)
{
    (void)in_sizes; (void)n_in; (void)out_size; (void)ws_size;
    const float* q  = (const float*)d_in[0];
    const float* k  = (const float*)d_in[1];
    const float* v  = (const float*)d_in[2];
    const float* Wq = (const float*)d_in[3];
    const float* bq = (const float*)d_in[4];
    const float* Wk = (const float*)d_in[5];
    const float* bk = (const float*)d_in[6];
    const float* Wv = (const float*)d_in[7];
    const float* bv = (const float*)d_in[8];
    const float* Wo = (const float*)d_in[9];
    const float* bo = (const float*)d_in[10];
    const void*  mk = d_in[11];

    float* ws   = (float*)d_ws;
    float* qhp  = ws + OFF_QHP;
    float* qkv  = ws + OFF_QK;
    float* qbv  = ws + OFF_QB;
    int*   flg  = (int*)(ws + OFF_FLAG);
    float* Sp   = ws + OFF_SP;
    float* S    = ws + OFF_S;
    float* att  = ws + OFF_ATT;
    float* ctxp = ws + OFF_CTXP;
    float* ctx  = ws + OFF_CTX;
    float* con  = ws + OFF_CON;
    float* out  = (float*)d_out;

    k_maskprobe<<<1, 1024, 0, stream>>>((const uint32_t*)mk, flg);
    k_qh<<<dim3(8, 16), 128, 0, stream>>>(q, Wq, qhp);
    k_qk<<<dim3(16, 8), 128, 0, stream>>>(qhp, bq, Wk, bk, qkv, qbv);
    k_scoresG2<<<dim3(64, 16), 256, 0, stream>>>(k, qkv, qbv, mk, flg, att, Sp);
    k_sred<<<2, 256, 0, stream>>>(Sp, S);
    k_ctx<<<dim3(256, 4), 256, 0, stream>>>(v, att, ctxp);
    k_ctxred<<<2048, 256, 0, stream>>>(ctxp, S, ctx);
    k_outh<<<dim3(4, NB, 2), 256, 0, stream>>>(ctx, Wv, bv, con);
    k_out<<<dim3(4, NB, 2), 256, 0, stream>>>(con, Wo, bo, out);
}